// Round 4
// baseline (37.876 us; speedup 1.0000x reference)
//
#include <hip/hip_runtime.h>
#include <hip/hip_bf16.h>

// CORAL ordinal-regression loss, mean-reduced.
// loss[i,k] = max(x,0) - x*[t_i > k] + log1p(exp(-|x|)),  x = logits[i,k]
//           = fmax(y,0) + log1p(exp(-|x|)),  y = (t_i > k) ? -x : x
// Log fusion per quad: sum_e log1p(e_e) = ln2 * log2( prod_e (1+e_e) ),
//   e_e = exp2(-log2e*|x_e|) in (0,1] -> each factor in (1,2], prod <= 16.
// out[0] = mean(loss)
//
// Mapping: 2 threads per row, NO division. gid < B -> quads 0..12 of row gid;
// gid >= B -> quads 13..24 of row gid-B. B = 262144 is divisible by 64 so the
// half-split is wave-uniform (no divergence). targets[row] loaded once per
// thread; quad loop fully unrolled -> loads use immediate offsets.

#define NTHREADS 256
#define QPR 25            // float4 quads per row (KM1=100)

__device__ __forceinline__ float hw_exp2(float a) { return __builtin_amdgcn_exp2f(a); }  // v_exp_f32
__device__ __forceinline__ float hw_log2(float a) { return __builtin_amdgcn_logf(a); }   // v_log_f32

__device__ __forceinline__ void coral_quad(const float4 x, const int t, const int kb,
                                           float& acc_relu, float& acc_l2) {
    const float c = -1.44269504088896f;  // -log2(e)
    const float e0 = hw_exp2(c * fabsf(x.x));
    const float e1 = hw_exp2(c * fabsf(x.y));
    const float e2 = hw_exp2(c * fabsf(x.z));
    const float e3 = hw_exp2(c * fabsf(x.w));
    acc_l2 += hw_log2(((1.f + e0) * (1.f + e1)) * ((1.f + e2) * (1.f + e3)));
    const float y0 = (t > kb    ) ? -x.x : x.x;
    const float y1 = (t > kb + 1) ? -x.y : x.y;
    const float y2 = (t > kb + 2) ? -x.z : x.z;
    const float y3 = (t > kb + 3) ? -x.w : x.w;
    acc_relu += fmaxf(y0, 0.f) + fmaxf(y1, 0.f) + fmaxf(y2, 0.f) + fmaxf(y3, 0.f);
}

__global__ __launch_bounds__(NTHREADS) void coral_partial_kernel(
    const float4* __restrict__ logits4,
    const int* __restrict__ targets,
    float* __restrict__ partials,
    int B)
{
    const int gid  = blockIdx.x * NTHREADS + threadIdx.x;   // [0, 2B)
    const int half = (gid >= B) ? 1 : 0;                    // wave-uniform
    const int row  = half ? gid - B : gid;
    const int t    = targets[row];
    const float4* __restrict__ p = logits4 + (size_t)row * QPR + (half ? 13 : 0);
    const int kb0  = half ? 52 : 0;

    float acc_relu = 0.0f;
    float acc_l2   = 0.0f;

    #pragma unroll
    for (int q = 0; q < 12; ++q)
        coral_quad(p[q], t, kb0 + 4 * q, acc_relu, acc_l2);
    if (!half)                      // wave-uniform branch: quad 12 (kb=48)
        coral_quad(p[12], t, 48, acc_relu, acc_l2);

    float acc = fmaf(0.69314718055995f, acc_l2, acc_relu);

    // wave64 butterfly reduce
    #pragma unroll
    for (int off = 32; off > 0; off >>= 1)
        acc += __shfl_down(acc, off, 64);

    __shared__ float s[NTHREADS / 64];
    const int lane = threadIdx.x & 63;
    const int wave = threadIdx.x >> 6;
    if (lane == 0) s[wave] = acc;
    __syncthreads();
    if (threadIdx.x == 0) {
        float b = 0.0f;
        #pragma unroll
        for (int w = 0; w < NTHREADS / 64; ++w) b += s[w];
        partials[blockIdx.x] = b;
    }
}

__global__ __launch_bounds__(NTHREADS) void coral_final_kernel(
    const float* __restrict__ partials,
    float* __restrict__ out,
    int n_partials,
    float inv_n)
{
    float acc = 0.0f;
    for (int i = threadIdx.x; i < n_partials; i += NTHREADS)
        acc += partials[i];

    #pragma unroll
    for (int off = 32; off > 0; off >>= 1)
        acc += __shfl_down(acc, off, 64);

    __shared__ float s[NTHREADS / 64];
    const int lane = threadIdx.x & 63;
    const int wave = threadIdx.x >> 6;
    if (lane == 0) s[wave] = acc;
    __syncthreads();
    if (threadIdx.x == 0) {
        float b = 0.0f;
        #pragma unroll
        for (int w = 0; w < NTHREADS / 64; ++w) b += s[w];
        out[0] = b * inv_n;
    }
}

extern "C" void kernel_launch(void* const* d_in, const int* in_sizes, int n_in,
                              void* d_out, int out_size, void* d_ws, size_t ws_size,
                              hipStream_t stream) {
    const float* logits  = (const float*)d_in[0];
    const int*   targets = (const int*)d_in[1];
    float* out = (float*)d_out;
    float* partials = (float*)d_ws;

    const int n_elems = in_sizes[0];            // B * KM1 = 26,214,400
    const int B       = in_sizes[1];            // 262,144 rows
    const float inv_n = 1.0f / (float)n_elems;

    const int n_threads_total = 2 * B;          // 2 threads per row
    const int n_blocks = n_threads_total / NTHREADS;   // 2048

    coral_partial_kernel<<<n_blocks, NTHREADS, 0, stream>>>(
        (const float4*)logits, targets, partials, B);
    coral_final_kernel<<<1, NTHREADS, 0, stream>>>(
        partials, out, n_blocks, inv_n);
}

// Round 5
// 29.582 us; speedup vs baseline: 1.2804x; 1.2804x over previous
//
#include <hip/hip_runtime.h>
#include <hip/hip_bf16.h>

// CORAL ordinal-regression loss, mean-reduced.
// loss[i,k] = max(x,0) - x*[t_i > k] + log1p(exp(-|x|)),  x = logits[i,k]
//           = fmax(y,0) + log1p(exp(-|x|)),  y = (t_i > k) ? -x : x
// Log fusion per quad: sum_e log1p(e_e) = ln2 * log2( prod_e (1+e_e) ),
//   e_e = exp2(-log2e*|x_e|) in (0,1] -> each factor in (1,2], prod <= 16.
// out[0] = mean(loss)
//
// Mapping: FLAT quad index (lane-coalesced, 4 cache lines per wave load —
// R4's row-per-thread stride-400B pattern was 64 lines/load and regressed).
// Exact batch: total_quads = 6,553,600 = QPT(5) * 1,310,720 threads
// -> 5120 blocks x 256, each thread does exactly 5 quads, fully unrolled,
// all 10 loads issued up front (deep MLP, one latency round-trip total).

#define NTHREADS 256
#define QPT 5             // quads per thread (exact path)

__device__ __forceinline__ float hw_exp2(float a) { return __builtin_amdgcn_exp2f(a); }  // v_exp_f32
__device__ __forceinline__ float hw_log2(float a) { return __builtin_amdgcn_logf(a); }   // v_log_f32

__device__ __forceinline__ void coral_quad(const float4 v, const int d,
                                           float& acc_relu, float& acc_l2) {
    const float c = -1.44269504088896f;  // -log2(e); abs folds into the mul
    const float e0 = hw_exp2(c * fabsf(v.x));
    const float e1 = hw_exp2(c * fabsf(v.y));
    const float e2 = hw_exp2(c * fabsf(v.z));
    const float e3 = hw_exp2(c * fabsf(v.w));
    acc_l2 += hw_log2(((1.f + e0) * (1.f + e1)) * ((1.f + e2) * (1.f + e3)));
    const float y0 = (d > 0) ? -v.x : v.x;
    const float y1 = (d > 1) ? -v.y : v.y;
    const float y2 = (d > 2) ? -v.z : v.z;
    const float y3 = (d > 3) ? -v.w : v.w;
    acc_relu += (fmaxf(y0, 0.f) + fmaxf(y1, 0.f)) + (fmaxf(y2, 0.f) + fmaxf(y3, 0.f));
}

__device__ __forceinline__ float block_reduce_epilogue(float acc, float* s) {
    #pragma unroll
    for (int off = 32; off > 0; off >>= 1)
        acc += __shfl_down(acc, off, 64);
    const int lane = threadIdx.x & 63;
    const int wave = threadIdx.x >> 6;
    if (lane == 0) s[wave] = acc;
    __syncthreads();
    float b = 0.0f;
    if (threadIdx.x == 0) {
        #pragma unroll
        for (int w = 0; w < NTHREADS / 64; ++w) b += s[w];
    }
    return b;
}

// Exact path: each thread handles quads {tid + k*stride, k=0..QPT-1}.
__global__ __launch_bounds__(NTHREADS) void coral_partial_exact(
    const float4* __restrict__ logits4,
    const int* __restrict__ targets,
    float* __restrict__ partials,
    int stride)                       // = total threads = total_quads / QPT
{
    const int tid = blockIdx.x * NTHREADS + threadIdx.x;

    float4 x[QPT];
    int    d[QPT];
    #pragma unroll
    for (int k = 0; k < QPT; ++k) {
        const int j   = tid + k * stride;
        const int row = j / 25;               // magic-mul
        const int kb  = (j - row * 25) * 4;
        x[k] = logits4[j];
        d[k] = targets[row] - kb;             // element c selected iff d > c
    }

    float acc_relu = 0.0f, acc_l2 = 0.0f;
    #pragma unroll
    for (int k = 0; k < QPT; ++k)
        coral_quad(x[k], d[k], acc_relu, acc_l2);

    float acc = fmaf(0.69314718055995f, acc_l2, acc_relu);

    __shared__ float s[NTHREADS / 64];
    const float b = block_reduce_epilogue(acc, s);
    if (threadIdx.x == 0) partials[blockIdx.x] = b;
}

// Fallback grid-stride path (only used if sizes aren't the expected ones).
__global__ __launch_bounds__(NTHREADS) void coral_partial_gs(
    const float4* __restrict__ logits4,
    const int* __restrict__ targets,
    float* __restrict__ partials,
    int total_quads)
{
    float acc_relu = 0.0f, acc_l2 = 0.0f;
    const int stride = gridDim.x * blockDim.x;
    for (int j = blockIdx.x * blockDim.x + threadIdx.x; j < total_quads; j += stride) {
        const int row = j / 25;
        const int kb  = (j - row * 25) * 4;
        coral_quad(logits4[j], targets[row] - kb, acc_relu, acc_l2);
    }
    float acc = fmaf(0.69314718055995f, acc_l2, acc_relu);

    __shared__ float s[NTHREADS / 64];
    const float b = block_reduce_epilogue(acc, s);
    if (threadIdx.x == 0) partials[blockIdx.x] = b;
}

__global__ __launch_bounds__(NTHREADS) void coral_final_kernel(
    const float* __restrict__ partials,
    float* __restrict__ out,
    int n_partials,
    float inv_n)
{
    float acc = 0.0f;
    for (int i = threadIdx.x; i < n_partials; i += NTHREADS)
        acc += partials[i];

    __shared__ float s[NTHREADS / 64];
    const float b = block_reduce_epilogue(acc, s);
    if (threadIdx.x == 0) out[0] = b * inv_n;
}

extern "C" void kernel_launch(void* const* d_in, const int* in_sizes, int n_in,
                              void* d_out, int out_size, void* d_ws, size_t ws_size,
                              hipStream_t stream) {
    const float* logits  = (const float*)d_in[0];
    const int*   targets = (const int*)d_in[1];
    float* out = (float*)d_out;
    float* partials = (float*)d_ws;

    const int n_elems     = in_sizes[0];          // B * KM1 = 26,214,400
    const int total_quads = n_elems / 4;          // 6,553,600
    const float inv_n = 1.0f / (float)n_elems;

    int n_blocks;
    if (total_quads % (QPT * NTHREADS) == 0) {
        const int n_threads_total = total_quads / QPT;      // 1,310,720
        n_blocks = n_threads_total / NTHREADS;              // 5120
        coral_partial_exact<<<n_blocks, NTHREADS, 0, stream>>>(
            (const float4*)logits, targets, partials, n_threads_total);
    } else {
        n_blocks = 2048;
        coral_partial_gs<<<n_blocks, NTHREADS, 0, stream>>>(
            (const float4*)logits, targets, partials, total_quads);
    }
    coral_final_kernel<<<1, NTHREADS, 0, stream>>>(
        partials, out, n_blocks, inv_n);
}

// Round 7
// 23.623 us; speedup vs baseline: 1.6034x; 1.2523x over previous
//
#include <hip/hip_runtime.h>
#include <hip/hip_bf16.h>

// CORAL ordinal-regression loss, mean-reduced.
// loss[i,k] = max(x,0) - x*[t_i > k] + log1p(exp(-|x|)),  x = logits[i,k]
//           = fmax(y,0) + log1p(exp(-|x|)),  y = (t_i > k) ? -x : x
// Log fusion per quad: sum_e log1p(e_e) = ln2 * log2( prod_e (1+e_e) ),
//   e_e = exp2(-log2e*|x_e|) in (0,1] -> each factor in (1,2], prod <= 16.
// out[0] = mean(loss)
//
// Mapping: FLAT quad index (lane-coalesced). Exact batch: total_quads =
// 6,553,600 = QPT(5) * 1,310,720 threads -> 5120 blocks x 256, each thread
// does exactly 5 quads, fully unrolled, all 10 loads issued up front.
// Logits are read-once per dispatch -> NONTEMPORAL loads (global_load nt)
// via clang ext_vector_type (HIP float4 is a struct, builtin rejects it).

#define NTHREADS 256
#define QPT 5             // quads per thread (exact path)

typedef float f32x4 __attribute__((ext_vector_type(4)));

__device__ __forceinline__ float hw_exp2(float a) { return __builtin_amdgcn_exp2f(a); }  // v_exp_f32
__device__ __forceinline__ float hw_log2(float a) { return __builtin_amdgcn_logf(a); }   // v_log_f32

__device__ __forceinline__ void coral_quad(const f32x4 v, const int d,
                                           float& acc_relu, float& acc_l2) {
    const float c = -1.44269504088896f;  // -log2(e); abs folds into the mul
    const float e0 = hw_exp2(c * fabsf(v.x));
    const float e1 = hw_exp2(c * fabsf(v.y));
    const float e2 = hw_exp2(c * fabsf(v.z));
    const float e3 = hw_exp2(c * fabsf(v.w));
    acc_l2 += hw_log2(((1.f + e0) * (1.f + e1)) * ((1.f + e2) * (1.f + e3)));
    const float y0 = (d > 0) ? -v.x : v.x;
    const float y1 = (d > 1) ? -v.y : v.y;
    const float y2 = (d > 2) ? -v.z : v.z;
    const float y3 = (d > 3) ? -v.w : v.w;
    acc_relu += (fmaxf(y0, 0.f) + fmaxf(y1, 0.f)) + (fmaxf(y2, 0.f) + fmaxf(y3, 0.f));
}

__device__ __forceinline__ float block_reduce_epilogue(float acc, float* s) {
    #pragma unroll
    for (int off = 32; off > 0; off >>= 1)
        acc += __shfl_down(acc, off, 64);
    const int lane = threadIdx.x & 63;
    const int wave = threadIdx.x >> 6;
    if (lane == 0) s[wave] = acc;
    __syncthreads();
    float b = 0.0f;
    if (threadIdx.x == 0) {
        #pragma unroll
        for (int w = 0; w < NTHREADS / 64; ++w) b += s[w];
    }
    return b;
}

// Exact path: each thread handles quads {tid + k*stride, k=0..QPT-1}.
__global__ __launch_bounds__(NTHREADS) void coral_partial_exact(
    const f32x4* __restrict__ logits4,
    const int* __restrict__ targets,
    float* __restrict__ partials,
    int stride)                       // = total threads = total_quads / QPT
{
    const int tid = blockIdx.x * NTHREADS + threadIdx.x;

    f32x4 x[QPT];
    int   d[QPT];
    #pragma unroll
    for (int k = 0; k < QPT; ++k) {
        const int j   = tid + k * stride;
        const int row = j / 25;               // magic-mul
        const int kb  = (j - row * 25) * 4;
        x[k] = __builtin_nontemporal_load(&logits4[j]);   // global_load_dwordx4 nt
        d[k] = targets[row] - kb;             // element c selected iff d > c
    }

    float acc_relu = 0.0f, acc_l2 = 0.0f;
    #pragma unroll
    for (int k = 0; k < QPT; ++k)
        coral_quad(x[k], d[k], acc_relu, acc_l2);

    float acc = fmaf(0.69314718055995f, acc_l2, acc_relu);

    __shared__ float s[NTHREADS / 64];
    const float b = block_reduce_epilogue(acc, s);
    if (threadIdx.x == 0) partials[blockIdx.x] = b;
}

// Fallback grid-stride path (only used if sizes aren't the expected ones).
__global__ __launch_bounds__(NTHREADS) void coral_partial_gs(
    const f32x4* __restrict__ logits4,
    const int* __restrict__ targets,
    float* __restrict__ partials,
    int total_quads)
{
    float acc_relu = 0.0f, acc_l2 = 0.0f;
    const int stride = gridDim.x * blockDim.x;
    for (int j = blockIdx.x * blockDim.x + threadIdx.x; j < total_quads; j += stride) {
        const int row = j / 25;
        const int kb  = (j - row * 25) * 4;
        coral_quad(logits4[j], targets[row] - kb, acc_relu, acc_l2);
    }
    float acc = fmaf(0.69314718055995f, acc_l2, acc_relu);

    __shared__ float s[NTHREADS / 64];
    const float b = block_reduce_epilogue(acc, s);
    if (threadIdx.x == 0) partials[blockIdx.x] = b;
}

// Final: n_partials is a multiple of 4 -> vector loads, 256 threads.
__global__ __launch_bounds__(NTHREADS) void coral_final_kernel(
    const f32x4* __restrict__ partials4,
    float* __restrict__ out,
    int n_quads,                       // n_partials / 4
    float inv_n)
{
    float acc = 0.0f;
    for (int i = threadIdx.x; i < n_quads; i += NTHREADS) {
        const f32x4 p = partials4[i];
        acc += (p.x + p.y) + (p.z + p.w);
    }

    __shared__ float s[NTHREADS / 64];
    const float b = block_reduce_epilogue(acc, s);
    if (threadIdx.x == 0) out[0] = b * inv_n;
}

extern "C" void kernel_launch(void* const* d_in, const int* in_sizes, int n_in,
                              void* d_out, int out_size, void* d_ws, size_t ws_size,
                              hipStream_t stream) {
    const float* logits  = (const float*)d_in[0];
    const int*   targets = (const int*)d_in[1];
    float* out = (float*)d_out;
    float* partials = (float*)d_ws;

    const int n_elems     = in_sizes[0];          // B * KM1 = 26,214,400
    const int total_quads = n_elems / 4;          // 6,553,600
    const float inv_n = 1.0f / (float)n_elems;

    int n_blocks;
    if (total_quads % (QPT * NTHREADS) == 0) {
        const int n_threads_total = total_quads / QPT;      // 1,310,720
        n_blocks = n_threads_total / NTHREADS;              // 5120
        coral_partial_exact<<<n_blocks, NTHREADS, 0, stream>>>(
            (const f32x4*)logits, targets, partials, n_threads_total);
    } else {
        n_blocks = 2048;
        coral_partial_gs<<<n_blocks, NTHREADS, 0, stream>>>(
            (const f32x4*)logits, targets, partials, total_quads);
    }
    coral_final_kernel<<<1, NTHREADS, 0, stream>>>(
        (const f32x4*)partials, out, n_blocks / 4, inv_n);
}